// Round 8
// baseline (584.235 us; speedup 1.0000x reference)
//
#include <hip/hip_runtime.h>
#include <hip/hip_bf16.h>

// NodeModelBase: per-edge MLP (Linear->LN->ReLU->Linear) + scatter_mean.
// Strategy: bf16 MFMA (16x16x32), swapped orientation D[n][e] = W^T * feat.
// R8: 2-TILE UNITS (32 edges/wave-iteration). Each weight-frag ds_read_b128
//     now feeds 2 MFMAs -> weight LDS traffic halves (3.2 GB -> 1.6 GB, was
//     the largest single pipe term ~34%). Paid for by dropping the raw A/B
//     feature-prefetch pipeline (R7 proved latency is TLP-hidden: occupancy
//     2x -> duration unchanged). Peak regs ~122 < 128 cap (4 waves/SIMD).
//     Indices still prefetched one unit ahead. hbuf reused tile-sequentially
//     (in-order per-wave DS execution). Kept: W1/W2 LDS frag-major
//     (register-resident weights spill: R1/R3), 1024-thr blocks @ 1 block/CU,
//     fused segmented-mean epilogue, separate preproc dispatches (R6 proved
//     in-kernel preproc at low occupancy costs 2.5x).

typedef __bf16 bf16x8 __attribute__((ext_vector_type(8)));
typedef float f32x4 __attribute__((ext_vector_type(4)));

#define LN_EPS 1e-5f

__device__ __forceinline__ unsigned short bfbits(float f) {
  return __builtin_bit_cast(unsigned short, (__bf16)f);
}
__device__ __forceinline__ float bflo(unsigned int u) { return __uint_as_float(u << 16); }
__device__ __forceinline__ float bfhi(unsigned int u) { return __uint_as_float(u & 0xffff0000u); }
__device__ __forceinline__ unsigned int pkbf(float a, float b) {
  return (unsigned int)bfbits(a) | ((unsigned int)bfbits(b) << 16);
}

// ---------------------------------------------------------------- histogram
__global__ void hist_kernel(const int* __restrict__ eidx, int* __restrict__ cnt, int E) {
  int e = blockIdx.x * blockDim.x + threadIdx.x;
  if (e < E) atomicAdd(&cnt[eidx[E + e]], 1);
}

// ------------------------------------------------------- exclusive scan (1 WG)
__global__ void scan_kernel(const int* __restrict__ cnt, int* __restrict__ off, int n) {
  __shared__ int wsum[16];
  __shared__ int carry_s;
  const int tid = threadIdx.x;
  const int wv = tid >> 6;
  const int ln = tid & 63;
  if (tid == 0) carry_s = 0;
  __syncthreads();
  for (int base = 0; base < n; base += 4096) {
    int i0 = base + tid * 4;
    int a = (i0 < n) ? cnt[i0] : 0;
    int b = (i0 + 1 < n) ? cnt[i0 + 1] : 0;
    int c = (i0 + 2 < n) ? cnt[i0 + 2] : 0;
    int d = (i0 + 3 < n) ? cnt[i0 + 3] : 0;
    int lsum = a + b + c + d;
    int sc = lsum;
#pragma unroll
    for (int dl = 1; dl < 64; dl <<= 1) {
      int t = __shfl_up(sc, dl);
      if (ln >= dl) sc += t;
    }
    if (ln == 63) wsum[wv] = sc;
    __syncthreads();
    int woff = 0;
#pragma unroll
    for (int w = 0; w < 16; ++w) {
      int t = wsum[w];
      if (w < wv) woff += t;
    }
    int excl = carry_s + woff + sc - lsum;
    if (i0 < n) off[i0] = excl;
    if (i0 + 1 < n) off[i0 + 1] = excl + a;
    if (i0 + 2 < n) off[i0 + 2] = excl + a + b;
    if (i0 + 3 < n) off[i0 + 3] = excl + a + b + c;
    __syncthreads();
    if (tid == 1023) carry_s = carry_s + woff + sc;
    __syncthreads();
  }
}

// ------------------------------------------------------------ bucket scatter
__global__ void scatter_kernel(const int* __restrict__ eidx, const int* __restrict__ off,
                               int* __restrict__ cur, int* __restrict__ perm, int E) {
  int e = blockIdx.x * blockDim.x + threadIdx.x;
  if (e < E) {
    int c = eidx[E + e];
    int p = atomicAdd(&cur[c], 1);
    perm[off[c] + p] = e;
  }
}

// ----------------------------------------------------------------- main MLP
template <bool ATOMIC>
__global__ __launch_bounds__(1024, 1) void mlp_kernel(
    const float* __restrict__ x, const float* __restrict__ ea,
    const int* __restrict__ eidx, const int* __restrict__ perm,
    const int* __restrict__ cnt, const float* __restrict__ W1,
    const float* __restrict__ b1, const float* __restrict__ lng,
    const float* __restrict__ lnb, const float* __restrict__ W2,
    const float* __restrict__ b2, float* __restrict__ out, int E, int ntiles) {
  // weights bf16 frag-major: chunk c = fragid*64 + lane, 16 B each -> 32 KB ea.
  __shared__ __align__(16) unsigned int w1L[2048 * 4];
  __shared__ __align__(16) unsigned int w2L[2048 * 4];
  __shared__ float b1L[128];
  __shared__ float b2L[128];
  __shared__ unsigned int glcL[128];  // low16 = bf16(ln_g), high16 = bf16(ln_b)
  // 16 rows * 272B (128 bf16 + 8 pad, keeps 16B alignment, breaks bank strides)
  __shared__ __align__(16) char hbuf[16][16 * 272];

  const int tid = threadIdx.x;
  const int lane = tid & 63;
  const int wv = tid >> 6;
  const int e15 = lane & 15;
  const int q = lane >> 4;
  char* hb = hbuf[wv];

  // ---- stage W1/W2 into LDS as MFMA A-fragments (bf16, frag-major) ----
  // Lane l of frag (ks,mt) holds W[k=ks*32+(l>>4)*8+j][n=mt*16+(l&15)], j=0..7
  for (int c = tid; c < 2048; c += 1024) {
    const int fragid = c >> 6;
    const int l = c & 63;
    const int ks = fragid >> 3, mt = fragid & 7;
    const int qq = l >> 4, ee = l & 15;
    const size_t base = (size_t)(ks * 32 + qq * 8) * 128 + mt * 16 + ee;
    unsigned int p1[4], p2[4];
#pragma unroll
    for (int jj = 0; jj < 4; ++jj) {
      p1[jj] = pkbf(W1[base + (size_t)(2 * jj) * 128], W1[base + (size_t)(2 * jj + 1) * 128]);
      p2[jj] = pkbf(W2[base + (size_t)(2 * jj) * 128], W2[base + (size_t)(2 * jj + 1) * 128]);
    }
    uint4 v1 = {p1[0], p1[1], p1[2], p1[3]};
    uint4 v2 = {p2[0], p2[1], p2[2], p2[3]};
    *(uint4*)&w1L[c * 4] = v1;
    *(uint4*)&w2L[c * 4] = v2;
  }
  if (tid < 128) {
    b1L[tid] = b1[tid];
    b2L[tid] = b2[tid];
    glcL[tid] = pkbf(lng[tid], lnb[tid]);
  }
  __syncthreads();

  const int nwav = (gridDim.x * blockDim.x) >> 6;
  const int wid = (blockIdx.x * blockDim.x + tid) >> 6;

  // load 16 feature float4s of one edge and convert to 4 bf16x8 B-fragments
  auto load_cvt = [&](int rowv, int ev, bf16x8 (&bfr)[4]) {
    const float* xr_ = x + (size_t)rowv * 64;
    const float* ar_ = ea + (size_t)ev * 64;
    float4 raw[8];
    raw[0] = *(const float4*)(xr_ + q * 8);
    raw[1] = *(const float4*)(xr_ + q * 8 + 4);
    raw[2] = *(const float4*)(xr_ + 32 + q * 8);
    raw[3] = *(const float4*)(xr_ + 32 + q * 8 + 4);
    raw[4] = *(const float4*)(ar_ + q * 8);
    raw[5] = *(const float4*)(ar_ + q * 8 + 4);
    raw[6] = *(const float4*)(ar_ + 32 + q * 8);
    raw[7] = *(const float4*)(ar_ + 32 + q * 8 + 4);
#pragma unroll
    for (int ks = 0; ks < 4; ++ks) {
      const float* p0 = (const float*)&raw[2 * ks];
      const float* p1 = (const float*)&raw[2 * ks + 1];
#pragma unroll
      for (int j = 0; j < 4; ++j) {
        bfr[ks][j] = (__bf16)p0[j];
        bfr[ks][4 + j] = (__bf16)p1[j];
      }
    }
  };

  // LN+ReLU one tile from c1, round-trip through hbuf, return B-frags hf
  auto ln_stage_hf = [&](f32x4 (&c1)[8], bf16x8 (&hf)[4]) {
    float s = 0.f, ss = 0.f;
#pragma unroll
    for (int mt = 0; mt < 8; ++mt)
#pragma unroll
      for (int r = 0; r < 4; ++r) {
        float v = c1[mt][r];
        s += v;
        ss += v * v;
      }
    s += __shfl_xor(s, 16);
    s += __shfl_xor(s, 32);
    ss += __shfl_xor(ss, 16);
    ss += __shfl_xor(ss, 32);
    const float mu = s * 0.0078125f;
    const float var = ss * 0.0078125f - mu * mu;
    const float inv = rsqrtf(var + LN_EPS);
#pragma unroll
    for (int mt = 0; mt < 8; ++mt) {
      uint4 gv = *(const uint4*)&glcL[mt * 16 + q * 4];
      unsigned int g[4] = {gv.x, gv.y, gv.z, gv.w};
      unsigned short u[4];
#pragma unroll
      for (int r = 0; r < 4; ++r) {
        float v = (c1[mt][r] - mu) * inv;
        v = v * bflo(g[r]) + bfhi(g[r]);
        v = fmaxf(v, 0.f);
        u[r] = bfbits(v);
      }
      uint2 w;
      w.x = (unsigned int)u[0] | ((unsigned int)u[1] << 16);
      w.y = (unsigned int)u[2] | ((unsigned int)u[3] << 16);
      *(uint2*)(hb + e15 * 272 + mt * 32 + q * 8) = w;
    }
#pragma unroll
    for (int ks = 0; ks < 4; ++ks)
      hf[ks] = __builtin_bit_cast(bf16x8, *(const uint4*)(hb + e15 * 272 + ks * 64 + q * 16));
  };

  // Fused segmented-mean epilogue: stage tile's 16 bf16 rows in LDS, then
  // run-length segment the 16 CSR positions by dest node (wave-uniform via
  // shfl from lanes 0-15) and atomically add seg_sum/deg into out.
  auto reduce_store = [&](const f32x4 (&c2)[8], int nd, float inv) {
#pragma unroll
    for (int mt = 0; mt < 8; ++mt) {
      unsigned short u[4];
#pragma unroll
      for (int r = 0; r < 4; ++r) u[r] = bfbits(c2[mt][r]);
      uint2 w;
      w.x = (unsigned int)u[0] | ((unsigned int)u[1] << 16);
      w.y = (unsigned int)u[2] | ((unsigned int)u[3] << 16);
      *(uint2*)(hb + e15 * 272 + mt * 32 + q * 8) = w;
    }
    float acc0 = 0.f, acc1 = 0.f;
    int curn = __shfl(nd, 0);
    float cinv = __shfl(inv, 0);
#pragma unroll
    for (int i = 0; i < 16; ++i) {
      int ni = __shfl(nd, i);
      float ii = __shfl(inv, i);
      if (ni != curn) {  // wave-uniform branch
        unsafeAtomicAdd(out + (size_t)curn * 128 + lane * 2, acc0 * cinv);
        unsafeAtomicAdd(out + (size_t)curn * 128 + lane * 2 + 1, acc1 * cinv);
        acc0 = 0.f;
        acc1 = 0.f;
        curn = ni;
        cinv = ii;
      }
      unsigned int v = *(const unsigned int*)(hb + i * 272 + lane * 4);
      acc0 += bflo(v);
      acc1 += bfhi(v);
    }
    unsafeAtomicAdd(out + (size_t)curn * 128 + lane * 2, acc0 * cinv);
    unsafeAtomicAdd(out + (size_t)curn * 128 + lane * 2 + 1, acc1 * cinv);
  };

  if constexpr (!ATOMIC) {
    const int nunits = ntiles >> 1;  // ntiles is even (E % 32 == 0)
    int u = wid;
    if (u >= nunits) return;
    // current unit's per-lane indices (edge e15 of tiles 2u, 2u+1)
    int pA = (2 * u) * 16 + e15;
    int pB = (2 * u + 1) * 16 + e15;
    int eA = perm[pA], eB = perm[pB];
    int rowA = eidx[eA], rowB = eidx[eB];
    int ndA = eidx[E + eA], ndB = eidx[E + eB];
    float invA = 1.f / (float)cnt[ndA];
    float invB = 1.f / (float)cnt[ndB];

    for (; u < nunits; u += nwav) {
      // ---- prefetch next unit's indices (hidden under this unit's compute)
      int un = u + nwav;
      int uc = (un < nunits) ? un : u;
      int pAn = (2 * uc) * 16 + e15;
      int pBn = (2 * uc + 1) * 16 + e15;
      int eAn = perm[pAn], eBn = perm[pBn];
      int rAn = eidx[eAn], rBn = eidx[eBn];
      int nAn = eidx[E + eAn], nBn = eidx[E + eBn];
      float iAn = 1.f / (float)cnt[nAn];
      float iBn = 1.f / (float)cnt[nBn];

      // ---- load + convert both tiles' features
      bf16x8 bfrA[4], bfrB[4];
      load_cvt(rowA, eA, bfrA);
      load_cvt(rowB, eB, bfrB);

      // ---- GEMM1 joint: one weight-frag read feeds both tiles
      f32x4 c1a[8], c1b[8];
#pragma unroll
      for (int mt = 0; mt < 8; ++mt) {
        float4 bv = *(const float4*)&b1L[mt * 16 + q * 4];
        c1a[mt][0] = bv.x; c1a[mt][1] = bv.y; c1a[mt][2] = bv.z; c1a[mt][3] = bv.w;
        c1b[mt] = c1a[mt];
      }
#pragma unroll
      for (int ks = 0; ks < 4; ++ks)
#pragma unroll
        for (int mt = 0; mt < 8; ++mt) {
          bf16x8 wf = __builtin_bit_cast(
              bf16x8, *(const uint4*)&w1L[((ks * 8 + mt) * 64 + lane) * 4]);
          c1a[mt] = __builtin_amdgcn_mfma_f32_16x16x32_bf16(wf, bfrA[ks], c1a[mt], 0, 0, 0);
          c1b[mt] = __builtin_amdgcn_mfma_f32_16x16x32_bf16(wf, bfrB[ks], c1b[mt], 0, 0, 0);
        }

      // ---- LN + hbuf round-trip, tile-sequential (hbuf reused; per-wave
      //      DS ops execute in order, so A's reads complete before B's writes)
      bf16x8 hfA[4], hfB[4];
      ln_stage_hf(c1a, hfA);
      ln_stage_hf(c1b, hfB);

      // ---- GEMM2 joint
      f32x4 c2a[8], c2b[8];
#pragma unroll
      for (int mt = 0; mt < 8; ++mt) {
        float4 bv = *(const float4*)&b2L[mt * 16 + q * 4];
        c2a[mt][0] = bv.x; c2a[mt][1] = bv.y; c2a[mt][2] = bv.z; c2a[mt][3] = bv.w;
        c2b[mt] = c2a[mt];
      }
#pragma unroll
      for (int ks = 0; ks < 4; ++ks)
#pragma unroll
        for (int mt = 0; mt < 8; ++mt) {
          bf16x8 wf = __builtin_bit_cast(
              bf16x8, *(const uint4*)&w2L[((ks * 8 + mt) * 64 + lane) * 4]);
          c2a[mt] = __builtin_amdgcn_mfma_f32_16x16x32_bf16(wf, hfA[ks], c2a[mt], 0, 0, 0);
          c2b[mt] = __builtin_amdgcn_mfma_f32_16x16x32_bf16(wf, hfB[ks], c2b[mt], 0, 0, 0);
        }

      // ---- fused segmented-mean epilogue, tile-sequential
      reduce_store(c2a, ndA, invA);
      reduce_store(c2b, ndB, invB);

      eA = eAn; rowA = rAn; ndA = nAn; invA = iAn;
      eB = eBn; rowB = rBn; ndB = nBn; invB = iBn;
    }
  } else {
    // fallback: fused atomic scatter of UNSCALED sums (divide_kernel follows)
    for (int t = wid; t < ntiles; t += nwav) {
      const int e = t * 16 + e15;
      const int row = eidx[e];
      const int cl = eidx[E + e];
      bf16x8 bfr[4];
      load_cvt(row, e, bfr);
      f32x4 c1[8];
#pragma unroll
      for (int mt = 0; mt < 8; ++mt) {
        float4 bv = *(const float4*)&b1L[mt * 16 + q * 4];
        c1[mt][0] = bv.x; c1[mt][1] = bv.y; c1[mt][2] = bv.z; c1[mt][3] = bv.w;
      }
#pragma unroll
      for (int ks = 0; ks < 4; ++ks)
#pragma unroll
        for (int mt = 0; mt < 8; ++mt) {
          bf16x8 wf = __builtin_bit_cast(
              bf16x8, *(const uint4*)&w1L[((ks * 8 + mt) * 64 + lane) * 4]);
          c1[mt] = __builtin_amdgcn_mfma_f32_16x16x32_bf16(wf, bfr[ks], c1[mt], 0, 0, 0);
        }
      bf16x8 hf[4];
      ln_stage_hf(c1, hf);
      f32x4 c2[8];
#pragma unroll
      for (int mt = 0; mt < 8; ++mt) {
        float4 bv = *(const float4*)&b2L[mt * 16 + q * 4];
        c2[mt][0] = bv.x; c2[mt][1] = bv.y; c2[mt][2] = bv.z; c2[mt][3] = bv.w;
      }
#pragma unroll
      for (int ks = 0; ks < 4; ++ks)
#pragma unroll
        for (int mt = 0; mt < 8; ++mt) {
          bf16x8 wf = __builtin_bit_cast(
              bf16x8, *(const uint4*)&w2L[((ks * 8 + mt) * 64 + lane) * 4]);
          c2[mt] = __builtin_amdgcn_mfma_f32_16x16x32_bf16(wf, hf[ks], c2[mt], 0, 0, 0);
        }
      float* op = out + (size_t)cl * 128 + q * 4;
#pragma unroll
      for (int mt = 0; mt < 8; ++mt)
#pragma unroll
        for (int r = 0; r < 4; ++r) unsafeAtomicAdd(op + mt * 16 + r, c2[mt][r]);
    }
  }
}

// ------------------------------------------------------ divide (atomic path)
__global__ void divide_kernel(float* __restrict__ out, const int* __restrict__ cnt, int N) {
  int i = blockIdx.x * blockDim.x + threadIdx.x;
  if (i >= N * 32) return;  // N*128/4 float4s
  int node = i >> 5;
  float s = 1.f / (float)(cnt[node] > 0 ? cnt[node] : 1);
  float4* p = (float4*)out + i;
  float4 v = *p;
  v.x *= s;
  v.y *= s;
  v.z *= s;
  v.w *= s;
  *p = v;
}

extern "C" void kernel_launch(void* const* d_in, const int* in_sizes, int n_in,
                              void* d_out, int out_size, void* d_ws, size_t ws_size,
                              hipStream_t stream) {
  const float* x = (const float*)d_in[0];
  const float* ea = (const float*)d_in[1];
  const int* eidx = (const int*)d_in[2];
  const float* W1 = (const float*)d_in[3];
  const float* b1 = (const float*)d_in[4];
  const float* lng = (const float*)d_in[5];
  const float* lnb = (const float*)d_in[6];
  const float* W2 = (const float*)d_in[7];
  const float* b2 = (const float*)d_in[8];
  float* out = (float*)d_out;

  const int N = in_sizes[0] / 64;   // 50000
  const int E = in_sizes[1] / 64;   // 800000
  const int ntiles = E / 16;
  const size_t permB = (size_t)E * 4;
  const size_t cB = (size_t)N * 4;
  const size_t need = permB + 3 * cB;  // perm + cnt/cur/off
  const int eblocks = (E + 255) / 256;

  if (ws_size >= need && (ntiles % 2) == 0) {
    // ---- CSR + fused segmented-mean path ----
    int* perm = (int*)d_ws;
    int* cnt = perm + E;
    int* cur = cnt + N;
    int* off = cur + N;
    hipMemsetAsync(out, 0, (size_t)out_size * 4, stream);
    hipMemsetAsync(cnt, 0, 2 * cB, stream);  // cnt + cur contiguous
    hist_kernel<<<eblocks, 256, 0, stream>>>(eidx, cnt, E);
    scan_kernel<<<1, 1024, 0, stream>>>(cnt, off, N);
    scatter_kernel<<<eblocks, 256, 0, stream>>>(eidx, off, cur, perm, E);
    mlp_kernel<false><<<256, 1024, 0, stream>>>(x, ea, eidx, perm, cnt, W1, b1,
                                                lng, lnb, W2, b2, out, E, ntiles);
  } else {
    // ---- fallback: fused atomic scatter (needs only N*4 bytes of ws) ----
    int* cnt = (int*)d_ws;
    hipMemsetAsync(out, 0, (size_t)out_size * 4, stream);
    hipMemsetAsync(cnt, 0, cB, stream);
    hist_kernel<<<eblocks, 256, 0, stream>>>(eidx, cnt, E);
    mlp_kernel<true><<<256, 1024, 0, stream>>>(x, ea, eidx, nullptr, cnt, W1, b1,
                                               lng, lnb, W2, b2, out, E, ntiles);
    divide_kernel<<<(N * 32 + 255) / 256, 256, 0, stream>>>(out, cnt, N);
  }
}

// Round 9
// 521.934 us; speedup vs baseline: 1.1194x; 1.1194x over previous
//
#include <hip/hip_runtime.h>
#include <hip/hip_bf16.h>

// NodeModelBase: per-edge MLP (Linear->LN->ReLU->Linear) + scatter_mean.
// Strategy: bf16 MFMA (16x16x32), swapped orientation D[n][e] = W^T * feat.
// R9: R8's 2-tile weight-reuse unit, but in 512-THREAD blocks. R8's failure:
//     a 1024-thr block FORCES 4 waves/SIMD residency -> 128-reg unified cap
//     (regardless of launch_bounds) -> ~190-reg unit spilled (~150MB extra
//     scratch R+W, mlp 254us). 512-thr block = 2 waves/SIMD minimum -> 256
//     cap; unit fits, no spill. R7 proved 2 vs 4 waves/SIMD is perf-neutral
//     here, and the 2-tile unit adds in-wave ILP. Each weight-frag
//     ds_read_b128 feeds 2 MFMAs -> weight LDS traffic halves (3.2->1.6GB).
//     LDS back to 101.9KB (hbuf[8]) -> 1 block/CU.
//     Kept: W1/W2 LDS frag-major, index prefetch one unit ahead, fused
//     segmented-mean epilogue, separate preproc dispatches.
//     Spill tripwire: FETCH >= 400MB means spill -> revert to R7.

typedef __bf16 bf16x8 __attribute__((ext_vector_type(8)));
typedef float f32x4 __attribute__((ext_vector_type(4)));

#define LN_EPS 1e-5f

__device__ __forceinline__ unsigned short bfbits(float f) {
  return __builtin_bit_cast(unsigned short, (__bf16)f);
}
__device__ __forceinline__ float bflo(unsigned int u) { return __uint_as_float(u << 16); }
__device__ __forceinline__ float bfhi(unsigned int u) { return __uint_as_float(u & 0xffff0000u); }
__device__ __forceinline__ unsigned int pkbf(float a, float b) {
  return (unsigned int)bfbits(a) | ((unsigned int)bfbits(b) << 16);
}

// ---------------------------------------------------------------- histogram
__global__ void hist_kernel(const int* __restrict__ eidx, int* __restrict__ cnt, int E) {
  int e = blockIdx.x * blockDim.x + threadIdx.x;
  if (e < E) atomicAdd(&cnt[eidx[E + e]], 1);
}

// ------------------------------------------------------- exclusive scan (1 WG)
__global__ void scan_kernel(const int* __restrict__ cnt, int* __restrict__ off, int n) {
  __shared__ int wsum[16];
  __shared__ int carry_s;
  const int tid = threadIdx.x;
  const int wv = tid >> 6;
  const int ln = tid & 63;
  if (tid == 0) carry_s = 0;
  __syncthreads();
  for (int base = 0; base < n; base += 4096) {
    int i0 = base + tid * 4;
    int a = (i0 < n) ? cnt[i0] : 0;
    int b = (i0 + 1 < n) ? cnt[i0 + 1] : 0;
    int c = (i0 + 2 < n) ? cnt[i0 + 2] : 0;
    int d = (i0 + 3 < n) ? cnt[i0 + 3] : 0;
    int lsum = a + b + c + d;
    int sc = lsum;
#pragma unroll
    for (int dl = 1; dl < 64; dl <<= 1) {
      int t = __shfl_up(sc, dl);
      if (ln >= dl) sc += t;
    }
    if (ln == 63) wsum[wv] = sc;
    __syncthreads();
    int woff = 0;
#pragma unroll
    for (int w = 0; w < 16; ++w) {
      int t = wsum[w];
      if (w < wv) woff += t;
    }
    int excl = carry_s + woff + sc - lsum;
    if (i0 < n) off[i0] = excl;
    if (i0 + 1 < n) off[i0 + 1] = excl + a;
    if (i0 + 2 < n) off[i0 + 2] = excl + a + b;
    if (i0 + 3 < n) off[i0 + 3] = excl + a + b + c;
    __syncthreads();
    if (tid == 1023) carry_s = carry_s + woff + sc;
    __syncthreads();
  }
}

// ------------------------------------------------------------ bucket scatter
__global__ void scatter_kernel(const int* __restrict__ eidx, const int* __restrict__ off,
                               int* __restrict__ cur, int* __restrict__ perm, int E) {
  int e = blockIdx.x * blockDim.x + threadIdx.x;
  if (e < E) {
    int c = eidx[E + e];
    int p = atomicAdd(&cur[c], 1);
    perm[off[c] + p] = e;
  }
}

// ----------------------------------------------------------------- main MLP
template <bool ATOMIC>
__global__ __launch_bounds__(512, 1) void mlp_kernel(
    const float* __restrict__ x, const float* __restrict__ ea,
    const int* __restrict__ eidx, const int* __restrict__ perm,
    const int* __restrict__ cnt, const float* __restrict__ W1,
    const float* __restrict__ b1, const float* __restrict__ lng,
    const float* __restrict__ lnb, const float* __restrict__ W2,
    const float* __restrict__ b2, float* __restrict__ out, int E, int ntiles) {
  // weights bf16 frag-major: chunk c = fragid*64 + lane, 16 B each -> 32 KB ea.
  __shared__ __align__(16) unsigned int w1L[2048 * 4];
  __shared__ __align__(16) unsigned int w2L[2048 * 4];
  __shared__ float b1L[128];
  __shared__ float b2L[128];
  __shared__ unsigned int glcL[128];  // low16 = bf16(ln_g), high16 = bf16(ln_b)
  // 16 rows * 272B (128 bf16 + 8 pad, keeps 16B alignment, breaks bank strides)
  __shared__ __align__(16) char hbuf[8][16 * 272];

  const int tid = threadIdx.x;
  const int lane = tid & 63;
  const int wv = tid >> 6;
  const int e15 = lane & 15;
  const int q = lane >> 4;
  char* hb = hbuf[wv];

  // ---- stage W1/W2 into LDS as MFMA A-fragments (bf16, frag-major) ----
  // Lane l of frag (ks,mt) holds W[k=ks*32+(l>>4)*8+j][n=mt*16+(l&15)], j=0..7
  for (int c = tid; c < 2048; c += 512) {
    const int fragid = c >> 6;
    const int l = c & 63;
    const int ks = fragid >> 3, mt = fragid & 7;
    const int qq = l >> 4, ee = l & 15;
    const size_t base = (size_t)(ks * 32 + qq * 8) * 128 + mt * 16 + ee;
    unsigned int p1[4], p2[4];
#pragma unroll
    for (int jj = 0; jj < 4; ++jj) {
      p1[jj] = pkbf(W1[base + (size_t)(2 * jj) * 128], W1[base + (size_t)(2 * jj + 1) * 128]);
      p2[jj] = pkbf(W2[base + (size_t)(2 * jj) * 128], W2[base + (size_t)(2 * jj + 1) * 128]);
    }
    uint4 v1 = {p1[0], p1[1], p1[2], p1[3]};
    uint4 v2 = {p2[0], p2[1], p2[2], p2[3]};
    *(uint4*)&w1L[c * 4] = v1;
    *(uint4*)&w2L[c * 4] = v2;
  }
  if (tid < 128) {
    b1L[tid] = b1[tid];
    b2L[tid] = b2[tid];
    glcL[tid] = pkbf(lng[tid], lnb[tid]);
  }
  __syncthreads();

  const int nwav = (gridDim.x * blockDim.x) >> 6;
  const int wid = (blockIdx.x * blockDim.x + tid) >> 6;

  // load 16 feature float4s of one edge and convert to 4 bf16x8 B-fragments
  auto load_cvt = [&](int rowv, int ev, bf16x8 (&bfr)[4]) {
    const float* xr_ = x + (size_t)rowv * 64;
    const float* ar_ = ea + (size_t)ev * 64;
    float4 raw[8];
    raw[0] = *(const float4*)(xr_ + q * 8);
    raw[1] = *(const float4*)(xr_ + q * 8 + 4);
    raw[2] = *(const float4*)(xr_ + 32 + q * 8);
    raw[3] = *(const float4*)(xr_ + 32 + q * 8 + 4);
    raw[4] = *(const float4*)(ar_ + q * 8);
    raw[5] = *(const float4*)(ar_ + q * 8 + 4);
    raw[6] = *(const float4*)(ar_ + 32 + q * 8);
    raw[7] = *(const float4*)(ar_ + 32 + q * 8 + 4);
#pragma unroll
    for (int ks = 0; ks < 4; ++ks) {
      const float* p0 = (const float*)&raw[2 * ks];
      const float* p1 = (const float*)&raw[2 * ks + 1];
#pragma unroll
      for (int j = 0; j < 4; ++j) {
        bfr[ks][j] = (__bf16)p0[j];
        bfr[ks][4 + j] = (__bf16)p1[j];
      }
    }
  };

  // LN+ReLU one tile from c1, round-trip through hbuf, return B-frags hf
  auto ln_stage_hf = [&](f32x4 (&c1)[8], bf16x8 (&hf)[4]) {
    float s = 0.f, ss = 0.f;
#pragma unroll
    for (int mt = 0; mt < 8; ++mt)
#pragma unroll
      for (int r = 0; r < 4; ++r) {
        float v = c1[mt][r];
        s += v;
        ss += v * v;
      }
    s += __shfl_xor(s, 16);
    s += __shfl_xor(s, 32);
    ss += __shfl_xor(ss, 16);
    ss += __shfl_xor(ss, 32);
    const float mu = s * 0.0078125f;
    const float var = ss * 0.0078125f - mu * mu;
    const float inv = rsqrtf(var + LN_EPS);
#pragma unroll
    for (int mt = 0; mt < 8; ++mt) {
      uint4 gv = *(const uint4*)&glcL[mt * 16 + q * 4];
      unsigned int g[4] = {gv.x, gv.y, gv.z, gv.w};
      unsigned short u[4];
#pragma unroll
      for (int r = 0; r < 4; ++r) {
        float v = (c1[mt][r] - mu) * inv;
        v = v * bflo(g[r]) + bfhi(g[r]);
        v = fmaxf(v, 0.f);
        u[r] = bfbits(v);
      }
      uint2 w;
      w.x = (unsigned int)u[0] | ((unsigned int)u[1] << 16);
      w.y = (unsigned int)u[2] | ((unsigned int)u[3] << 16);
      *(uint2*)(hb + e15 * 272 + mt * 32 + q * 8) = w;
    }
#pragma unroll
    for (int ks = 0; ks < 4; ++ks)
      hf[ks] = __builtin_bit_cast(bf16x8, *(const uint4*)(hb + e15 * 272 + ks * 64 + q * 16));
  };

  // Fused segmented-mean epilogue: stage tile's 16 bf16 rows in LDS, then
  // run-length segment the 16 CSR positions by dest node (wave-uniform via
  // shfl from lanes 0-15) and atomically add seg_sum/deg into out.
  auto reduce_store = [&](const f32x4 (&c2)[8], int nd, float inv) {
#pragma unroll
    for (int mt = 0; mt < 8; ++mt) {
      unsigned short u[4];
#pragma unroll
      for (int r = 0; r < 4; ++r) u[r] = bfbits(c2[mt][r]);
      uint2 w;
      w.x = (unsigned int)u[0] | ((unsigned int)u[1] << 16);
      w.y = (unsigned int)u[2] | ((unsigned int)u[3] << 16);
      *(uint2*)(hb + e15 * 272 + mt * 32 + q * 8) = w;
    }
    float acc0 = 0.f, acc1 = 0.f;
    int curn = __shfl(nd, 0);
    float cinv = __shfl(inv, 0);
#pragma unroll
    for (int i = 0; i < 16; ++i) {
      int ni = __shfl(nd, i);
      float ii = __shfl(inv, i);
      if (ni != curn) {  // wave-uniform branch
        unsafeAtomicAdd(out + (size_t)curn * 128 + lane * 2, acc0 * cinv);
        unsafeAtomicAdd(out + (size_t)curn * 128 + lane * 2 + 1, acc1 * cinv);
        acc0 = 0.f;
        acc1 = 0.f;
        curn = ni;
        cinv = ii;
      }
      unsigned int v = *(const unsigned int*)(hb + i * 272 + lane * 4);
      acc0 += bflo(v);
      acc1 += bfhi(v);
    }
    unsafeAtomicAdd(out + (size_t)curn * 128 + lane * 2, acc0 * cinv);
    unsafeAtomicAdd(out + (size_t)curn * 128 + lane * 2 + 1, acc1 * cinv);
  };

  if constexpr (!ATOMIC) {
    const int nunits = ntiles >> 1;  // ntiles is even (E % 32 == 0)
    int u = wid;
    if (u >= nunits) return;
    // current unit's per-lane indices (edge e15 of tiles 2u, 2u+1)
    int pA = (2 * u) * 16 + e15;
    int pB = (2 * u + 1) * 16 + e15;
    int eA = perm[pA], eB = perm[pB];
    int rowA = eidx[eA], rowB = eidx[eB];
    int ndA = eidx[E + eA], ndB = eidx[E + eB];
    float invA = 1.f / (float)cnt[ndA];
    float invB = 1.f / (float)cnt[ndB];

    for (; u < nunits; u += nwav) {
      // ---- prefetch next unit's indices (hidden under this unit's compute)
      int un = u + nwav;
      int uc = (un < nunits) ? un : u;
      int pAn = (2 * uc) * 16 + e15;
      int pBn = (2 * uc + 1) * 16 + e15;
      int eAn = perm[pAn], eBn = perm[pBn];
      int rAn = eidx[eAn], rBn = eidx[eBn];
      int nAn = eidx[E + eAn], nBn = eidx[E + eBn];
      float iAn = 1.f / (float)cnt[nAn];
      float iBn = 1.f / (float)cnt[nBn];

      // ---- load + convert both tiles' features
      bf16x8 bfrA[4], bfrB[4];
      load_cvt(rowA, eA, bfrA);
      load_cvt(rowB, eB, bfrB);

      // ---- GEMM1 joint: one weight-frag read feeds both tiles
      f32x4 c1a[8], c1b[8];
#pragma unroll
      for (int mt = 0; mt < 8; ++mt) {
        float4 bv = *(const float4*)&b1L[mt * 16 + q * 4];
        c1a[mt][0] = bv.x; c1a[mt][1] = bv.y; c1a[mt][2] = bv.z; c1a[mt][3] = bv.w;
        c1b[mt] = c1a[mt];
      }
#pragma unroll
      for (int ks = 0; ks < 4; ++ks)
#pragma unroll
        for (int mt = 0; mt < 8; ++mt) {
          bf16x8 wf = __builtin_bit_cast(
              bf16x8, *(const uint4*)&w1L[((ks * 8 + mt) * 64 + lane) * 4]);
          c1a[mt] = __builtin_amdgcn_mfma_f32_16x16x32_bf16(wf, bfrA[ks], c1a[mt], 0, 0, 0);
          c1b[mt] = __builtin_amdgcn_mfma_f32_16x16x32_bf16(wf, bfrB[ks], c1b[mt], 0, 0, 0);
        }

      // ---- LN + hbuf round-trip, tile-sequential (hbuf reused; per-wave
      //      DS ops execute in order, so A's reads complete before B's writes)
      bf16x8 hfA[4], hfB[4];
      ln_stage_hf(c1a, hfA);
      ln_stage_hf(c1b, hfB);

      // ---- GEMM2 joint
      f32x4 c2a[8], c2b[8];
#pragma unroll
      for (int mt = 0; mt < 8; ++mt) {
        float4 bv = *(const float4*)&b2L[mt * 16 + q * 4];
        c2a[mt][0] = bv.x; c2a[mt][1] = bv.y; c2a[mt][2] = bv.z; c2a[mt][3] = bv.w;
        c2b[mt] = c2a[mt];
      }
#pragma unroll
      for (int ks = 0; ks < 4; ++ks)
#pragma unroll
        for (int mt = 0; mt < 8; ++mt) {
          bf16x8 wf = __builtin_bit_cast(
              bf16x8, *(const uint4*)&w2L[((ks * 8 + mt) * 64 + lane) * 4]);
          c2a[mt] = __builtin_amdgcn_mfma_f32_16x16x32_bf16(wf, hfA[ks], c2a[mt], 0, 0, 0);
          c2b[mt] = __builtin_amdgcn_mfma_f32_16x16x32_bf16(wf, hfB[ks], c2b[mt], 0, 0, 0);
        }

      // ---- fused segmented-mean epilogue, tile-sequential
      reduce_store(c2a, ndA, invA);
      reduce_store(c2b, ndB, invB);

      eA = eAn; rowA = rAn; ndA = nAn; invA = iAn;
      eB = eBn; rowB = rBn; ndB = nBn; invB = iBn;
    }
  } else {
    // fallback: fused atomic scatter of UNSCALED sums (divide_kernel follows)
    for (int t = wid; t < ntiles; t += nwav) {
      const int e = t * 16 + e15;
      const int row = eidx[e];
      const int cl = eidx[E + e];
      bf16x8 bfr[4];
      load_cvt(row, e, bfr);
      f32x4 c1[8];
#pragma unroll
      for (int mt = 0; mt < 8; ++mt) {
        float4 bv = *(const float4*)&b1L[mt * 16 + q * 4];
        c1[mt][0] = bv.x; c1[mt][1] = bv.y; c1[mt][2] = bv.z; c1[mt][3] = bv.w;
      }
#pragma unroll
      for (int ks = 0; ks < 4; ++ks)
#pragma unroll
        for (int mt = 0; mt < 8; ++mt) {
          bf16x8 wf = __builtin_bit_cast(
              bf16x8, *(const uint4*)&w1L[((ks * 8 + mt) * 64 + lane) * 4]);
          c1[mt] = __builtin_amdgcn_mfma_f32_16x16x32_bf16(wf, bfr[ks], c1[mt], 0, 0, 0);
        }
      bf16x8 hf[4];
      ln_stage_hf(c1, hf);
      f32x4 c2[8];
#pragma unroll
      for (int mt = 0; mt < 8; ++mt) {
        float4 bv = *(const float4*)&b2L[mt * 16 + q * 4];
        c2[mt][0] = bv.x; c2[mt][1] = bv.y; c2[mt][2] = bv.z; c2[mt][3] = bv.w;
      }
#pragma unroll
      for (int ks = 0; ks < 4; ++ks)
#pragma unroll
        for (int mt = 0; mt < 8; ++mt) {
          bf16x8 wf = __builtin_bit_cast(
              bf16x8, *(const uint4*)&w2L[((ks * 8 + mt) * 64 + lane) * 4]);
          c2[mt] = __builtin_amdgcn_mfma_f32_16x16x32_bf16(wf, hf[ks], c2[mt], 0, 0, 0);
        }
      float* op = out + (size_t)cl * 128 + q * 4;
#pragma unroll
      for (int mt = 0; mt < 8; ++mt)
#pragma unroll
        for (int r = 0; r < 4; ++r) unsafeAtomicAdd(op + mt * 16 + r, c2[mt][r]);
    }
  }
}

// ------------------------------------------------------ divide (atomic path)
__global__ void divide_kernel(float* __restrict__ out, const int* __restrict__ cnt, int N) {
  int i = blockIdx.x * blockDim.x + threadIdx.x;
  if (i >= N * 32) return;  // N*128/4 float4s
  int node = i >> 5;
  float s = 1.f / (float)(cnt[node] > 0 ? cnt[node] : 1);
  float4* p = (float4*)out + i;
  float4 v = *p;
  v.x *= s;
  v.y *= s;
  v.z *= s;
  v.w *= s;
  *p = v;
}

extern "C" void kernel_launch(void* const* d_in, const int* in_sizes, int n_in,
                              void* d_out, int out_size, void* d_ws, size_t ws_size,
                              hipStream_t stream) {
  const float* x = (const float*)d_in[0];
  const float* ea = (const float*)d_in[1];
  const int* eidx = (const int*)d_in[2];
  const float* W1 = (const float*)d_in[3];
  const float* b1 = (const float*)d_in[4];
  const float* lng = (const float*)d_in[5];
  const float* lnb = (const float*)d_in[6];
  const float* W2 = (const float*)d_in[7];
  const float* b2 = (const float*)d_in[8];
  float* out = (float*)d_out;

  const int N = in_sizes[0] / 64;   // 50000
  const int E = in_sizes[1] / 64;   // 800000
  const int ntiles = E / 16;
  const size_t permB = (size_t)E * 4;
  const size_t cB = (size_t)N * 4;
  const size_t need = permB + 3 * cB;  // perm + cnt/cur/off
  const int eblocks = (E + 255) / 256;

  if (ws_size >= need && (ntiles % 2) == 0) {
    // ---- CSR + fused segmented-mean path ----
    int* perm = (int*)d_ws;
    int* cnt = perm + E;
    int* cur = cnt + N;
    int* off = cur + N;
    hipMemsetAsync(out, 0, (size_t)out_size * 4, stream);
    hipMemsetAsync(cnt, 0, 2 * cB, stream);  // cnt + cur contiguous
    hist_kernel<<<eblocks, 256, 0, stream>>>(eidx, cnt, E);
    scan_kernel<<<1, 1024, 0, stream>>>(cnt, off, N);
    scatter_kernel<<<eblocks, 256, 0, stream>>>(eidx, off, cur, perm, E);
    mlp_kernel<false><<<256, 512, 0, stream>>>(x, ea, eidx, perm, cnt, W1, b1,
                                               lng, lnb, W2, b2, out, E, ntiles);
  } else {
    // ---- fallback: fused atomic scatter (needs only N*4 bytes of ws) ----
    int* cnt = (int*)d_ws;
    hipMemsetAsync(out, 0, (size_t)out_size * 4, stream);
    hipMemsetAsync(cnt, 0, cB, stream);
    hist_kernel<<<eblocks, 256, 0, stream>>>(eidx, cnt, E);
    mlp_kernel<true><<<256, 512, 0, stream>>>(x, ea, eidx, nullptr, cnt, W1, b1,
                                              lng, lnb, W2, b2, out, E, ntiles);
    divide_kernel<<<(N * 32 + 255) / 256, 256, 0, stream>>>(out, cnt, N);
  }
}